// Round 8
// baseline (769.988 us; speedup 1.0000x reference)
//
#include <hip/hip_runtime.h>
#include <hip/hip_bf16.h>

// Problem constants
#define NB   64      // batch N
#define TT   12      // T
#define VV   256     // V (vertices)
#define CIN  64
#define COUT 64
#define VSQ  65536   // V*V
#define WT   16      // w-tile per block (fused kernel)
#define VC   16      // v-chunk (fused kernel)

typedef float f32x4 __attribute__((ext_vector_type(4)));

// ---------------------------------------------------------------------------
// K1: y[n,o,t,v] = sum_c x[n,c,t,v] * conv_w[o,c] + conv_b[o]
// block = (n*T + t), 256 threads (thread = v). Proven ~20 us (BW floor).
// ---------------------------------------------------------------------------
__global__ __launch_bounds__(256) void k1_conv(
    const float* __restrict__ x, const float* __restrict__ w,
    const float* __restrict__ b, float* __restrict__ y)
{
    const int nt = blockIdx.x;
    const int n  = nt / TT;
    const int t  = nt % TT;
    const int v  = threadIdx.x;

    const float* xp = x + ((long)n * CIN * TT + t) * VV + v;
    float xv[CIN];
    #pragma unroll 8
    for (int c = 0; c < CIN; ++c)
        xv[c] = xp[(long)c * TT * VV];          // coalesced

    float* yp = y + ((long)n * COUT * TT + t) * VV + v;

    for (int o0 = 0; o0 < COUT; o0 += 16) {
        float acc[16];
        #pragma unroll
        for (int i = 0; i < 16; ++i) acc[i] = b[o0 + i];
        #pragma unroll 8
        for (int c = 0; c < CIN; ++c) {
            const float xc = xv[c];
            #pragma unroll
            for (int i = 0; i < 16; ++i)
                acc[i] += w[(o0 + i) * CIN + c] * xc;   // uniform -> s_load
        }
        #pragma unroll
        for (int i = 0; i < 16; ++i)
            yp[(long)(o0 + i) * TT * VV] = acc[i];
    }
}

// ---------------------------------------------------------------------------
// K23 fused: per (n, 16-w-tile) block, loop over v in chunks of 16.
// Phase A (thread = (vj,wj)): full MLP for position (v0+vj, w0+wj);
//   nontemporal-store Aw[n,:,v,w] to global (write-once output) and deposit
//   the 64 values into a swizzled 64 KB LDS tile.
// Phase B (thread = (cb,wg)): acc[t][4w] += y[n,cb,t,v] * Aw_lds[cb][v][wq]
//   for the 16 v's of the chunk; y read from global (L2, 16x reuse).
// The 1.07 GB Aw HBM re-read of the 2-kernel scheme disappears.
// Swizzle: word index L ^= (c&7)<<2 — scalar writes land anywhere; b128
// reads stay contiguous (XOR only touches bits >=2); spreads the 1KB-strided
// c-rows across all 32 banks (conflict-free-optimal for b128).
// ---------------------------------------------------------------------------
__global__ __launch_bounds__(256) void k23_fused(
    const float* __restrict__ A,
    const float* __restrict__ w1, const float* __restrict__ b1,
    const float* __restrict__ w2, const float* __restrict__ b2,
    const float* __restrict__ w3, const float* __restrict__ b3,
    const float* __restrict__ y,
    float* __restrict__ Aw, float* __restrict__ out)
{
    __shared__ float awt[COUT * VC * WT];   // 64 KiB

    const int n   = blockIdx.x >> 4;
    const int w0  = (blockIdx.x & 15) * WT;
    const int tid = threadIdx.x;

    const int vj = tid >> 4;       // phase A v-offset   0..15
    const int wj = tid & 15;       // phase A w-offset   0..15
    const int cb = tid >> 2;       // phase B c          0..63
    const int wg = tid & 3;        // phase B w-quad     0..3

    f32x4 acc[TT];
    #pragma unroll
    for (int t = 0; t < TT; ++t) acc[t] = (f32x4)(0.f);

    const float* ybase  = y + ((long)(n * COUT + cb) * TT) * VV;
    const float* Abase  = A + ((long)n * 8 << 16);
    float*       awbase = Aw + ((long)n * COUT << 16);

    for (int v0 = 0; v0 < VV; v0 += VC) {
        // ---------------- phase A : MLP ----------------
        const int pos = (v0 + vj) * VV + (w0 + wj);
        const float* ap = Abase + pos;
        float f[7];
        #pragma unroll
        for (int c = 0; c < 7; ++c) f[c] = ap[(long)c << 16];
        const float m = ap[(long)7 << 16];

        float h1[16];
        #pragma unroll
        for (int o = 0; o < 16; ++o) {
            float s = b1[o];
            #pragma unroll
            for (int k = 0; k < 7; ++k) s += w1[o * 7 + k] * f[k];   // uniform
            h1[o] = fmaxf(s, 0.f);
        }
        float h2[32];
        #pragma unroll
        for (int o = 0; o < 32; ++o) {
            float s = b2[o];
            #pragma unroll
            for (int k = 0; k < 16; ++k) s += w2[o * 16 + k] * h1[k]; // uniform
            h2[o] = fmaxf(s, 0.f);
        }
        for (int o0 = 0; o0 < 64; o0 += 16) {       // NOT unrolled: small live set
            float a16[16];
            #pragma unroll
            for (int i = 0; i < 16; ++i) a16[i] = b3[o0 + i];
            #pragma unroll
            for (int k = 0; k < 32; ++k) {
                #pragma unroll
                for (int i = 0; i < 16; ++i)
                    a16[i] += w3[(o0 + i) * 32 + k] * h2[k];          // uniform
            }
            #pragma unroll
            for (int i = 0; i < 16; ++i) {
                const int c = o0 + i;
                const float av = fmaxf(a16[i], 0.f) * m;
                __builtin_nontemporal_store(av, awbase + ((long)c << 16) + pos);
                const int L = (c * (VC * WT) + vj * WT + wj) ^ ((c & 7) << 2);
                awt[L] = av;
            }
        }
        __syncthreads();

        // ---------------- phase B : einsum partial ----------------
        f32x4 awv[VC];
        #pragma unroll
        for (int vv = 0; vv < VC; ++vv) {
            const int L = (cb * (VC * WT) + vv * WT + wg * 4) ^ ((cb & 7) << 2);
            awv[vv] = *reinterpret_cast<const f32x4*>(&awt[L]);
        }
        #pragma unroll
        for (int t = 0; t < TT; ++t) {
            #pragma unroll
            for (int q = 0; q < 4; ++q) {
                const f32x4 yv = *reinterpret_cast<const f32x4*>(ybase + t * VV + v0 + q * 4);
                acc[t] += yv.x * awv[q * 4 + 0] + yv.y * awv[q * 4 + 1]
                        + yv.z * awv[q * 4 + 2] + yv.w * awv[q * 4 + 3];
            }
        }
        __syncthreads();   // protect awt before next chunk's writes
    }

    float* obase = out + ((long)(n * COUT + cb) * TT) * VV + w0 + wg * 4;
    #pragma unroll
    for (int t = 0; t < TT; ++t)
        __builtin_nontemporal_store(acc[t], reinterpret_cast<f32x4*>(obase + t * VV));
}

// ---------------------------------------------------------------------------
// Fallback path (ws too small): R7's proven K2 + K3.
// ---------------------------------------------------------------------------
__global__ __launch_bounds__(256, 5) void k2_mlp(
    const float* __restrict__ A,
    const float* __restrict__ w1, const float* __restrict__ b1,
    const float* __restrict__ w2, const float* __restrict__ b2,
    const float* __restrict__ w3, const float* __restrict__ b3,
    float* __restrict__ Aw)
{
    const long idx = (long)blockIdx.x * 256 + threadIdx.x;
    const int  n   = (int)(idx >> 16);
    const int  rem = (int)(idx & (VSQ - 1));

    const float* ap = A + ((long)n * 8 << 16) + rem;
    float f[7];
    #pragma unroll
    for (int c = 0; c < 7; ++c) f[c] = ap[(long)c << 16];
    const float m = ap[(long)7 << 16];

    float h1[16];
    #pragma unroll
    for (int o = 0; o < 16; ++o) {
        float acc = b1[o];
        #pragma unroll
        for (int k = 0; k < 7; ++k) acc += w1[o * 7 + k] * f[k];
        h1[o] = fmaxf(acc, 0.f);
    }
    float h2[32];
    #pragma unroll
    for (int o = 0; o < 32; ++o) {
        float acc = b2[o];
        #pragma unroll
        for (int k = 0; k < 16; ++k) acc += w2[o * 16 + k] * h1[k];
        h2[o] = fmaxf(acc, 0.f);
    }
    float* op = Aw + ((long)n * COUT << 16) + rem;
    for (int o0 = 0; o0 < 64; o0 += 8) {
        float acc[8];
        #pragma unroll
        for (int i = 0; i < 8; ++i) acc[i] = b3[o0 + i];
        #pragma unroll
        for (int k = 0; k < 32; ++k) {
            #pragma unroll
            for (int i = 0; i < 8; ++i)
                acc[i] += w3[(o0 + i) * 32 + k] * h2[k];
        }
        #pragma unroll
        for (int i = 0; i < 8; ++i)
            __builtin_nontemporal_store(fmaxf(acc[i], 0.f) * m,
                                        op + ((long)(o0 + i) << 16));
    }
}

__global__ __launch_bounds__(256) void k3_einsum(
    const float* __restrict__ Aw, const float* __restrict__ y,
    float* __restrict__ out)
{
    __shared__ float ys[4][TT][VV];

    const int n   = blockIdx.x >> 4;
    const int c0  = (blockIdx.x & 15) * 4;
    const int tid = threadIdx.x;
    const int cq  = tid >> 6;
    const int w4  = (tid & 63) * 4;

    {
        const float* src = y + ((long)(n * COUT + c0) * TT) * VV;
        float* dst = &ys[0][0][0];
        #pragma unroll
        for (int it = 0; it < 12; ++it) {
            const int idx = tid + it * 256;
            *reinterpret_cast<float4*>(dst + idx * 4) =
                *reinterpret_cast<const float4*>(src + idx * 4);
        }
    }
    __syncthreads();

    const float* awp = Aw + (((long)(n * COUT + c0 + cq)) << 16) + w4;
    float4 acc[TT];
    #pragma unroll
    for (int t = 0; t < TT; ++t) acc[t] = make_float4(0.f, 0.f, 0.f, 0.f);

    for (int v0 = 0; v0 < VV; v0 += 4) {
        float4 xs[TT];
        #pragma unroll
        for (int t = 0; t < TT; ++t)
            xs[t] = *reinterpret_cast<const float4*>(&ys[cq][t][v0]);

        const f32x4 aw0 = __builtin_nontemporal_load(
            reinterpret_cast<const f32x4*>(awp + (long)(v0 + 0) * VV));
        const f32x4 aw1 = __builtin_nontemporal_load(
            reinterpret_cast<const f32x4*>(awp + (long)(v0 + 1) * VV));
        const f32x4 aw2 = __builtin_nontemporal_load(
            reinterpret_cast<const f32x4*>(awp + (long)(v0 + 2) * VV));
        const f32x4 aw3 = __builtin_nontemporal_load(
            reinterpret_cast<const f32x4*>(awp + (long)(v0 + 3) * VV));

        #pragma unroll
        for (int t = 0; t < TT; ++t) {
            acc[t].x += xs[t].x * aw0.x + xs[t].y * aw1.x + xs[t].z * aw2.x + xs[t].w * aw3.x;
            acc[t].y += xs[t].x * aw0.y + xs[t].y * aw1.y + xs[t].z * aw2.y + xs[t].w * aw3.y;
            acc[t].z += xs[t].x * aw0.z + xs[t].y * aw1.z + xs[t].z * aw2.z + xs[t].w * aw3.z;
            acc[t].w += xs[t].x * aw0.w + xs[t].y * aw1.w + xs[t].z * aw2.w + xs[t].w * aw3.w;
        }
    }

    float* op = out + ((long)(n * COUT + c0 + cq) * TT) * VV + w4;
    #pragma unroll
    for (int t = 0; t < TT; ++t)
        *reinterpret_cast<float4*>(op + t * VV) = acc[t];
}

// ---------------------------------------------------------------------------
extern "C" void kernel_launch(void* const* d_in, const int* in_sizes, int n_in,
                              void* d_out, int out_size, void* d_ws, size_t ws_size,
                              hipStream_t stream)
{
    const float* x      = (const float*)d_in[0];
    const float* A      = (const float*)d_in[1];
    const float* conv_w = (const float*)d_in[2];
    const float* conv_b = (const float*)d_in[3];
    const float* w1     = (const float*)d_in[4];
    const float* b1     = (const float*)d_in[5];
    const float* w2     = (const float*)d_in[6];
    const float* b2     = (const float*)d_in[7];
    const float* w3     = (const float*)d_in[8];
    const float* b3     = (const float*)d_in[9];

    float* out = (float*)d_out;                                  // (64,64,12,256)
    float* Aw  = (float*)d_out + (long)NB * COUT * TT * VV;      // (64,64,256,256)
    const size_t y_bytes = (size_t)NB * COUT * TT * VV * sizeof(float);

    if (ws_size >= y_bytes) {
        float* y = (float*)d_ws;
        k1_conv<<<NB * TT, 256, 0, stream>>>(x, conv_w, conv_b, y);
        k23_fused<<<NB * (VV / WT), 256, 0, stream>>>(
            A, w1, b1, w2, b2, w3, b3, y, Aw, out);
    } else {
        // fallback: 3-kernel path (k3 handles out==y aliasing)
        k1_conv<<<NB * TT, 256, 0, stream>>>(x, conv_w, conv_b, out);
        k2_mlp<<<(NB * VSQ) / 256, 256, 0, stream>>>(A, w1, b1, w2, b2, w3, b3, Aw);
        k3_einsum<<<NB * (COUT / 4), 256, 0, stream>>>(Aw, out, out);
    }
}

// Round 9
// 668.087 us; speedup vs baseline: 1.1525x; 1.1525x over previous
//
#include <hip/hip_runtime.h>
#include <hip/hip_bf16.h>

// Problem constants
#define NB   64      // batch N
#define TT   12      // T
#define VV   256     // V (vertices)
#define CIN  64
#define COUT 64
#define VSQ  65536   // V*V
#define PP   256     // positions per k2 block

typedef float f32x4 __attribute__((ext_vector_type(4)));

// ---------------------------------------------------------------------------
// K1: y[n,o,t,v] = sum_c x[n,c,t,v] * conv_w[o,c] + conv_b[o]
// block = (n*T + t), 256 threads (thread = v). Proven ~20 us (BW floor).
// ---------------------------------------------------------------------------
__global__ __launch_bounds__(256) void k1_conv(
    const float* __restrict__ x, const float* __restrict__ w,
    const float* __restrict__ b, float* __restrict__ y)
{
    const int nt = blockIdx.x;
    const int n  = nt / TT;
    const int t  = nt % TT;
    const int v  = threadIdx.x;

    const float* xp = x + ((long)n * CIN * TT + t) * VV + v;
    float xv[CIN];
    #pragma unroll 8
    for (int c = 0; c < CIN; ++c)
        xv[c] = xp[(long)c * TT * VV];          // coalesced

    float* yp = y + ((long)n * COUT * TT + t) * VV + v;

    for (int o0 = 0; o0 < COUT; o0 += 16) {
        float acc[16];
        #pragma unroll
        for (int i = 0; i < 16; ++i) acc[i] = b[o0 + i];
        #pragma unroll 8
        for (int c = 0; c < CIN; ++c) {
            const float xc = xv[c];
            #pragma unroll
            for (int i = 0; i < 16; ++i)
                acc[i] += w[(o0 + i) * CIN + c] * xc;   // uniform -> s_load
        }
        #pragma unroll
        for (int i = 0; i < 16; ++i)
            yp[(long)(o0 + i) * TT * VV] = acc[i];
    }
}

// ---------------------------------------------------------------------------
// K2 redesigned: two-phase, layer-3 weights VGPR-resident.
// Phase 1 (thread = position): h2[32] via cheap layers 1-2 (624 FMA), written
//   to LDS transposed h2s[32][260] (write: lanes consecutive, conflict-free;
//   read: b128 of 4 consecutive positions, 2-way = free). Mask to LDS too.
// Phase 2 (thread = (c-quad, pos-lane)): w3r[4][32] loaded ONCE into 128
//   VGPRs; per pos-quad: 32x { 1 ds_read_b128 h2 -> 16 FMA } (1:16 supply
//   ratio), then relu*mask + nontemporal f32x4 store (row-contiguous).
// Kills the per-position streaming of the 2048 layer-3 weights that rocprof
// showed as ~2.7x VALU inflation (R8: VALUBusy 67%).
// ---------------------------------------------------------------------------
__global__ __launch_bounds__(256) void k2_mlp(
    const float* __restrict__ A,
    const float* __restrict__ w1, const float* __restrict__ b1,
    const float* __restrict__ w2, const float* __restrict__ b2,
    const float* __restrict__ w3, const float* __restrict__ b3,
    float* __restrict__ Aw)
{
    __shared__ float h2s[32][260];   // transposed, padded: 33.3 KiB
    __shared__ float ms[PP];         // mask

    const int  tid  = threadIdx.x;
    const long gpos = (long)blockIdx.x * PP;       // n*VSQ + rem0
    const int  n    = (int)(gpos >> 16);
    const int  rem0 = (int)(gpos & (VSQ - 1));

    // ---------------- phase 1: h2 for position rem0+tid ----------------
    {
        const float* ap = A + ((long)n * 8 << 16) + rem0 + tid;
        float f[7];
        #pragma unroll
        for (int c = 0; c < 7; ++c) f[c] = ap[(long)c << 16];   // coalesced
        ms[tid] = ap[(long)7 << 16];

        float h1[16];
        #pragma unroll
        for (int o = 0; o < 16; ++o) {
            float s = b1[o];
            #pragma unroll
            for (int k = 0; k < 7; ++k) s += w1[o * 7 + k] * f[k];   // uniform
            h1[o] = fmaxf(s, 0.f);
        }
        #pragma unroll
        for (int o = 0; o < 32; ++o) {
            float s = b2[o];
            #pragma unroll
            for (int k = 0; k < 16; ++k) s += w2[o * 16 + k] * h1[k]; // uniform
            h2s[o][tid] = fmaxf(s, 0.f);    // conflict-free (consecutive lanes)
        }
    }
    __syncthreads();

    // ---------------- phase 2: layer 3, w3 in VGPRs ----------------
    const int cq = tid >> 4;        // c-quad 0..15  -> c = 4cq..4cq+3
    const int pl = tid & 15;        // pos-lane 0..15

    float w3r[4][32];               // 128 VGPRs, loaded once
    #pragma unroll
    for (int i = 0; i < 4; ++i) {
        #pragma unroll
        for (int k4 = 0; k4 < 32; k4 += 4) {
            const f32x4 wv = *reinterpret_cast<const f32x4*>(&w3[(cq * 4 + i) * 32 + k4]);
            w3r[i][k4 + 0] = wv.x; w3r[i][k4 + 1] = wv.y;
            w3r[i][k4 + 2] = wv.z; w3r[i][k4 + 3] = wv.w;
        }
    }
    const float bb0 = b3[cq * 4 + 0], bb1 = b3[cq * 4 + 1];
    const float bb2 = b3[cq * 4 + 2], bb3 = b3[cq * 4 + 3];

    float* awbase = Aw + ((long)n * COUT << 16) + rem0;

    #pragma unroll
    for (int iter = 0; iter < 4; ++iter) {
        const int q = pl + iter * 16;          // pos-quad index 0..63
        f32x4 a0 = (f32x4)(bb0), a1 = (f32x4)(bb1);
        f32x4 a2 = (f32x4)(bb2), a3 = (f32x4)(bb3);
        #pragma unroll
        for (int k = 0; k < 32; ++k) {
            const f32x4 h = *reinterpret_cast<const f32x4*>(&h2s[k][q * 4]);
            a0 += w3r[0][k] * h;
            a1 += w3r[1][k] * h;
            a2 += w3r[2][k] * h;
            a3 += w3r[3][k] * h;
        }
        const f32x4 m4 = *reinterpret_cast<const f32x4*>(&ms[q * 4]);
        f32x4 r0, r1, r2, r3;
        #pragma unroll
        for (int j = 0; j < 4; ++j) {
            r0[j] = fmaxf(a0[j], 0.f) * m4[j];
            r1[j] = fmaxf(a1[j], 0.f) * m4[j];
            r2[j] = fmaxf(a2[j], 0.f) * m4[j];
            r3[j] = fmaxf(a3[j], 0.f) * m4[j];
        }
        const int pq = q * 4;
        __builtin_nontemporal_store(r0, reinterpret_cast<f32x4*>(awbase + ((long)(cq * 4 + 0) << 16) + pq));
        __builtin_nontemporal_store(r1, reinterpret_cast<f32x4*>(awbase + ((long)(cq * 4 + 1) << 16) + pq));
        __builtin_nontemporal_store(r2, reinterpret_cast<f32x4*>(awbase + ((long)(cq * 4 + 2) << 16) + pq));
        __builtin_nontemporal_store(r3, reinterpret_cast<f32x4*>(awbase + ((long)(cq * 4 + 3) << 16) + pq));
    }
}

// ---------------------------------------------------------------------------
// K3: out[n,c,t,w] = sum_v y[n,c,t,v] * Aw[n,c,v,w]   (R7 proven, ~245 us)
// block = (n, c-quad), 48 KB LDS y tiles; per v-group-4: 12 broadcast
// ds_read_b128 + 4 coalesced 16B nt Aw loads -> 192 FMAs. In-place safe.
// ---------------------------------------------------------------------------
__global__ __launch_bounds__(256) void k3_einsum(
    const float* __restrict__ Aw, const float* __restrict__ y,
    float* __restrict__ out)
{
    __shared__ float ys[4][TT][VV];

    const int n   = blockIdx.x >> 4;
    const int c0  = (blockIdx.x & 15) * 4;
    const int tid = threadIdx.x;
    const int cq  = tid >> 6;
    const int w4  = (tid & 63) * 4;

    {
        const float* src = y + ((long)(n * COUT + c0) * TT) * VV;
        float* dst = &ys[0][0][0];
        #pragma unroll
        for (int it = 0; it < 12; ++it) {
            const int idx = tid + it * 256;
            *reinterpret_cast<float4*>(dst + idx * 4) =
                *reinterpret_cast<const float4*>(src + idx * 4);
        }
    }
    __syncthreads();

    const float* awp = Aw + (((long)(n * COUT + c0 + cq)) << 16) + w4;
    float4 acc[TT];
    #pragma unroll
    for (int t = 0; t < TT; ++t) acc[t] = make_float4(0.f, 0.f, 0.f, 0.f);

    for (int v0 = 0; v0 < VV; v0 += 4) {
        float4 xs[TT];
        #pragma unroll
        for (int t = 0; t < TT; ++t)
            xs[t] = *reinterpret_cast<const float4*>(&ys[cq][t][v0]);

        const f32x4 aw0 = __builtin_nontemporal_load(
            reinterpret_cast<const f32x4*>(awp + (long)(v0 + 0) * VV));
        const f32x4 aw1 = __builtin_nontemporal_load(
            reinterpret_cast<const f32x4*>(awp + (long)(v0 + 1) * VV));
        const f32x4 aw2 = __builtin_nontemporal_load(
            reinterpret_cast<const f32x4*>(awp + (long)(v0 + 2) * VV));
        const f32x4 aw3 = __builtin_nontemporal_load(
            reinterpret_cast<const f32x4*>(awp + (long)(v0 + 3) * VV));

        #pragma unroll
        for (int t = 0; t < TT; ++t) {
            acc[t].x += xs[t].x * aw0.x + xs[t].y * aw1.x + xs[t].z * aw2.x + xs[t].w * aw3.x;
            acc[t].y += xs[t].x * aw0.y + xs[t].y * aw1.y + xs[t].z * aw2.y + xs[t].w * aw3.y;
            acc[t].z += xs[t].x * aw0.z + xs[t].y * aw1.z + xs[t].z * aw2.z + xs[t].w * aw3.z;
            acc[t].w += xs[t].x * aw0.w + xs[t].y * aw1.w + xs[t].z * aw2.w + xs[t].w * aw3.w;
        }
    }

    float* op = out + ((long)(n * COUT + c0 + cq) * TT) * VV + w4;
    #pragma unroll
    for (int t = 0; t < TT; ++t)
        *reinterpret_cast<float4*>(op + t * VV) = acc[t];
}

// ---------------------------------------------------------------------------
extern "C" void kernel_launch(void* const* d_in, const int* in_sizes, int n_in,
                              void* d_out, int out_size, void* d_ws, size_t ws_size,
                              hipStream_t stream)
{
    const float* x      = (const float*)d_in[0];
    const float* A      = (const float*)d_in[1];
    const float* conv_w = (const float*)d_in[2];
    const float* conv_b = (const float*)d_in[3];
    const float* w1     = (const float*)d_in[4];
    const float* b1     = (const float*)d_in[5];
    const float* w2     = (const float*)d_in[6];
    const float* b2     = (const float*)d_in[7];
    const float* w3     = (const float*)d_in[8];
    const float* b3     = (const float*)d_in[9];

    float* out = (float*)d_out;                                  // (64,64,12,256)
    float* Aw  = (float*)d_out + (long)NB * COUT * TT * VV;      // (64,64,256,256)
    const size_t y_bytes = (size_t)NB * COUT * TT * VV * sizeof(float);

    float* y = (ws_size >= y_bytes) ? (float*)d_ws : out;        // k3 handles alias

    // K1: conv -> y
    k1_conv<<<NB * TT, 256, 0, stream>>>(x, conv_w, conv_b, y);

    // K2: MLP + mask -> Aw (two-phase, w3 in VGPRs)
    k2_mlp<<<(NB * VSQ) / PP, 256, 0, stream>>>(A, w1, b1, w2, b2, w3, b3, Aw);

    // K3: einsum (in-place safe if y == out)
    k3_einsum<<<NB * (COUT / 4), 256, 0, stream>>>(Aw, y, out);
}

// Round 10
// 638.802 us; speedup vs baseline: 1.2054x; 1.0458x over previous
//
#include <hip/hip_runtime.h>
#include <hip/hip_bf16.h>

// Problem constants
#define NB   64      // batch N
#define TT   12      // T
#define VV   256     // V (vertices)
#define CIN  64
#define COUT 64
#define VSQ  65536   // V*V

typedef float f32x4 __attribute__((ext_vector_type(4)));
using s16x8 = __attribute__((ext_vector_type(8))) short;   // 8 bf16 (4 VGPRs)

__device__ __forceinline__ unsigned short f2bf(float f) {
    union { __hip_bfloat16 h; unsigned short u; } cv;
    cv.h = __float2bfloat16(f);          // RNE
    return cv.u;
}

// ---------------------------------------------------------------------------
// K1: y[n,o,t,v] = sum_c x[n,c,t,v] * conv_w[o,c] + conv_b[o]
// block = (n*T + t), 256 threads (thread = v). Proven ~20 us (BW floor).
// ---------------------------------------------------------------------------
__global__ __launch_bounds__(256) void k1_conv(
    const float* __restrict__ x, const float* __restrict__ w,
    const float* __restrict__ b, float* __restrict__ y)
{
    const int nt = blockIdx.x;
    const int n  = nt / TT;
    const int t  = nt % TT;
    const int v  = threadIdx.x;

    const float* xp = x + ((long)n * CIN * TT + t) * VV + v;
    float xv[CIN];
    #pragma unroll 8
    for (int c = 0; c < CIN; ++c)
        xv[c] = xp[(long)c * TT * VV];          // coalesced

    float* yp = y + ((long)n * COUT * TT + t) * VV + v;

    for (int o0 = 0; o0 < COUT; o0 += 16) {
        float acc[16];
        #pragma unroll
        for (int i = 0; i < 16; ++i) acc[i] = b[o0 + i];
        #pragma unroll 8
        for (int c = 0; c < CIN; ++c) {
            const float xc = xv[c];
            #pragma unroll
            for (int i = 0; i < 16; ++i)
                acc[i] += w[(o0 + i) * CIN + c] * xc;   // uniform -> s_load
        }
        #pragma unroll
        for (int i = 0; i < 16; ++i)
            yp[(long)(o0 + i) * TT * VV] = acc[i];
    }
}

// ---------------------------------------------------------------------------
// K2 with MFMA layer-3.
// Phase 1 (thread = position, 256 pos/block): h2[32] on VALU (624 FMA),
//   bf16-packed into a PRE-SWIZZLED LDS A-fragment tile so phase 2's loads
//   are one conflict-free ds_read_b128 per lane per M-tile.
//   Element k of position p (tile m=p/16, row r=p%16) lives at lane
//   lam=(k/8)*16+r, slot k%8 -> word addr m*256 + (k/8)*64 + r*4 + (k%8)/2.
// Phase 2 (4 waves x 4 M-tiles x 4 N-tiles): one mfma_f32_16x16x32_bf16 per
//   16x16 output tile (K=32 = full hidden dim). B-frag: lane l holds
//   w3[c0+(l&15)][8*(l>>4)+i]. C-init = b3. Epilogue: relu * mask, f32x4
//   nontemporal store (C layout: col=lane&15, row=(lane>>4)*4+reg).
// Moves 2048 of 2672 FMAs/position from the VALU to the (idle) matrix pipe.
// ---------------------------------------------------------------------------
__global__ __launch_bounds__(256) void k2_mlp(
    const float* __restrict__ A,
    const float* __restrict__ w1, const float* __restrict__ b1,
    const float* __restrict__ w2, const float* __restrict__ b2,
    const float* __restrict__ w3, const float* __restrict__ b3,
    float* __restrict__ Aw)
{
    __shared__ unsigned int afrag[16 * 256];   // 16 KiB A-fragments
    __shared__ float ms[256];                  // mask per position

    const int  tid  = threadIdx.x;
    const long gpos = (long)blockIdx.x * 256;      // n*VSQ + rem0
    const int  n    = (int)(gpos >> 16);
    const int  rem0 = (int)(gpos & (VSQ - 1));

    // ---------------- phase 1: h2 for position rem0+tid ----------------
    {
        const float* ap = A + ((long)n * 8 << 16) + rem0 + tid;
        float f[7];
        #pragma unroll
        for (int c = 0; c < 7; ++c) f[c] = ap[(long)c << 16];   // coalesced
        ms[tid] = ap[(long)7 << 16];

        float h1[16];
        #pragma unroll
        for (int o = 0; o < 16; ++o) {
            float s = b1[o];
            #pragma unroll
            for (int k = 0; k < 7; ++k) s += w1[o * 7 + k] * f[k];   // uniform
            h1[o] = fmaxf(s, 0.f);
        }
        float h2[32];
        #pragma unroll
        for (int o = 0; o < 32; ++o) {
            float s = b2[o];
            #pragma unroll
            for (int k = 0; k < 16; ++k) s += w2[o * 16 + k] * h1[k]; // uniform
            h2[o] = fmaxf(s, 0.f);
        }

        const int m = tid >> 4;        // M-tile
        const int r = tid & 15;        // row within tile
        #pragma unroll
        for (int kk = 0; kk < 16; ++kk) {   // bf16 pair (k=2kk, 2kk+1)
            const unsigned int pr = (unsigned int)f2bf(h2[2 * kk])
                                  | ((unsigned int)f2bf(h2[2 * kk + 1]) << 16);
            afrag[m * 256 + (kk >> 2) * 64 + r * 4 + (kk & 3)] = pr;
        }
    }
    __syncthreads();

    // ---------------- phase 2: layer 3 on the matrix pipe ----------------
    const int lane = tid & 63;
    const int wave = tid >> 6;
    const int lc   = lane & 15;        // output column lane (c within tile)
    const int lq   = lane >> 4;        // quarter (k-group / row-group)

    // B-fragments + biases for the 4 N-tiles (built once, from global w3)
    s16x8 bfr[4];
    float bias[4];
    #pragma unroll
    for (int ntile = 0; ntile < 4; ++ntile) {
        const int c = ntile * 16 + lc;
        const float* wr = w3 + c * 32 + lq * 8;
        s16x8 bf;
        #pragma unroll
        for (int i = 0; i < 8; ++i) bf[i] = (short)f2bf(wr[i]);
        bfr[ntile]  = bf;
        bias[ntile] = b3[c];
    }

    float* awbase = Aw + ((long)n * COUT << 16) + rem0;

    #pragma unroll
    for (int j = 0; j < 4; ++j) {
        const int mt = wave * 4 + j;
        const s16x8 afr = *reinterpret_cast<const s16x8*>(&afrag[mt * 256 + lane * 4]);
        const int pbase = mt * 16 + lq * 4;                 // position base (x4)
        const f32x4 mv = *reinterpret_cast<const f32x4*>(&ms[pbase]);
        #pragma unroll
        for (int ntile = 0; ntile < 4; ++ntile) {
            f32x4 acc = (f32x4)(bias[ntile]);
            acc = __builtin_amdgcn_mfma_f32_16x16x32_bf16(afr, bfr[ntile], acc, 0, 0, 0);
            f32x4 r;
            #pragma unroll
            for (int u = 0; u < 4; ++u) r[u] = fmaxf(acc[u], 0.f) * mv[u];
            __builtin_nontemporal_store(r, reinterpret_cast<f32x4*>(
                awbase + ((long)(ntile * 16 + lc) << 16) + pbase));
        }
    }
}

// ---------------------------------------------------------------------------
// K3: out[n,c,t,w] = sum_v y[n,c,t,v] * Aw[n,c,v,w]   (R7 proven, ~245 us)
// block = (n, c-quad), 48 KB LDS y tiles; per v-group-4: 12 broadcast
// ds_read_b128 + 4 coalesced 16B nt Aw loads -> 192 FMAs. In-place safe.
// ---------------------------------------------------------------------------
__global__ __launch_bounds__(256) void k3_einsum(
    const float* __restrict__ Aw, const float* __restrict__ y,
    float* __restrict__ out)
{
    __shared__ float ys[4][TT][VV];

    const int n   = blockIdx.x >> 4;
    const int c0  = (blockIdx.x & 15) * 4;
    const int tid = threadIdx.x;
    const int cq  = tid >> 6;
    const int w4  = (tid & 63) * 4;

    {
        const float* src = y + ((long)(n * COUT + c0) * TT) * VV;
        float* dst = &ys[0][0][0];
        #pragma unroll
        for (int it = 0; it < 12; ++it) {
            const int idx = tid + it * 256;
            *reinterpret_cast<float4*>(dst + idx * 4) =
                *reinterpret_cast<const float4*>(src + idx * 4);
        }
    }
    __syncthreads();

    const float* awp = Aw + (((long)(n * COUT + c0 + cq)) << 16) + w4;
    float4 acc[TT];
    #pragma unroll
    for (int t = 0; t < TT; ++t) acc[t] = make_float4(0.f, 0.f, 0.f, 0.f);

    for (int v0 = 0; v0 < VV; v0 += 4) {
        float4 xs[TT];
        #pragma unroll
        for (int t = 0; t < TT; ++t)
            xs[t] = *reinterpret_cast<const float4*>(&ys[cq][t][v0]);

        const f32x4 aw0 = __builtin_nontemporal_load(
            reinterpret_cast<const f32x4*>(awp + (long)(v0 + 0) * VV));
        const f32x4 aw1 = __builtin_nontemporal_load(
            reinterpret_cast<const f32x4*>(awp + (long)(v0 + 1) * VV));
        const f32x4 aw2 = __builtin_nontemporal_load(
            reinterpret_cast<const f32x4*>(awp + (long)(v0 + 2) * VV));
        const f32x4 aw3 = __builtin_nontemporal_load(
            reinterpret_cast<const f32x4*>(awp + (long)(v0 + 3) * VV));

        #pragma unroll
        for (int t = 0; t < TT; ++t) {
            acc[t].x += xs[t].x * aw0.x + xs[t].y * aw1.x + xs[t].z * aw2.x + xs[t].w * aw3.x;
            acc[t].y += xs[t].x * aw0.y + xs[t].y * aw1.y + xs[t].z * aw2.y + xs[t].w * aw3.y;
            acc[t].z += xs[t].x * aw0.z + xs[t].y * aw1.z + xs[t].z * aw2.z + xs[t].w * aw3.z;
            acc[t].w += xs[t].x * aw0.w + xs[t].y * aw1.w + xs[t].z * aw2.w + xs[t].w * aw3.w;
        }
    }

    float* op = out + ((long)(n * COUT + c0 + cq) * TT) * VV + w4;
    #pragma unroll
    for (int t = 0; t < TT; ++t)
        *reinterpret_cast<float4*>(op + t * VV) = acc[t];
}

// ---------------------------------------------------------------------------
extern "C" void kernel_launch(void* const* d_in, const int* in_sizes, int n_in,
                              void* d_out, int out_size, void* d_ws, size_t ws_size,
                              hipStream_t stream)
{
    const float* x      = (const float*)d_in[0];
    const float* A      = (const float*)d_in[1];
    const float* conv_w = (const float*)d_in[2];
    const float* conv_b = (const float*)d_in[3];
    const float* w1     = (const float*)d_in[4];
    const float* b1     = (const float*)d_in[5];
    const float* w2     = (const float*)d_in[6];
    const float* b2     = (const float*)d_in[7];
    const float* w3     = (const float*)d_in[8];
    const float* b3     = (const float*)d_in[9];

    float* out = (float*)d_out;                                  // (64,64,12,256)
    float* Aw  = (float*)d_out + (long)NB * COUT * TT * VV;      // (64,64,256,256)
    const size_t y_bytes = (size_t)NB * COUT * TT * VV * sizeof(float);

    float* y = (ws_size >= y_bytes) ? (float*)d_ws : out;        // k3 handles alias

    // K1: conv -> y
    k1_conv<<<NB * TT, 256, 0, stream>>>(x, conv_w, conv_b, y);

    // K2: MLP + mask -> Aw (layer 3 on MFMA)
    k2_mlp<<<(NB * VSQ) / 256, 256, 0, stream>>>(A, w1, b1, w2, b2, w3, b3, Aw);

    // K3: einsum (in-place safe if y == out)
    k3_einsum<<<NB * (COUT / 4), 256, 0, stream>>>(Aw, y, out);
}